// Round 6
// baseline (2089.277 us; speedup 1.0000x reference)
//
#include <hip/hip_runtime.h>
#include <hip/hip_bf16.h>

#define N_NODES 50000
#define N_EDGES 800000
#define DIN 128
#define DH   256
#define DOUT 128
#define EPSV 1e-5f
#define SLOPE 0.01f
#define SCAN_NB ((N_NODES + 255) / 256)   // 196

typedef __bf16 bf16x8 __attribute__((ext_vector_type(8)));
typedef __bf16 bf16x4 __attribute__((ext_vector_type(4)));
typedef float  f32x4  __attribute__((ext_vector_type(4)));

// ---------------- cast f32 -> bf16 (weights and x) ----------------
__global__ void cast_kernel(const float* __restrict__ src, __bf16* __restrict__ dst, int n4) {
    int i = blockIdx.x * blockDim.x + threadIdx.x;
    if (i < n4) {
        float4 v = ((const float4*)src)[i];
        bf16x4 o; o[0] = (__bf16)v.x; o[1] = (__bf16)v.y; o[2] = (__bf16)v.z; o[3] = (__bf16)v.w;
        ((bf16x4*)dst)[i] = o;
    }
}

// ---------------- CSR build ----------------
__global__ void deg_kernel(const int* __restrict__ dst, int* __restrict__ deg) {
    int i = blockIdx.x * blockDim.x + threadIdx.x;
    if (i < N_EDGES) atomicAdd(&deg[dst[i]], 1);
}

__global__ void dinv_kernel(const int* __restrict__ deg, float* __restrict__ dinv) {
    int i = blockIdx.x * blockDim.x + threadIdx.x;
    if (i < N_NODES) dinv[i] = rsqrtf((float)deg[i] + 1.0f);  // +1 self-loop
}

__global__ __launch_bounds__(256) void scan_bsum(const int* __restrict__ deg,
                                                 int* __restrict__ bsum) {
    __shared__ int lds[256];
    int i = blockIdx.x * 256 + threadIdx.x;
    lds[threadIdx.x] = (i < N_NODES) ? deg[i] + 1 : 0;
    __syncthreads();
    #pragma unroll
    for (int off = 128; off > 0; off >>= 1) {
        if (threadIdx.x < off) lds[threadIdx.x] += lds[threadIdx.x + off];
        __syncthreads();
    }
    if (threadIdx.x == 0) bsum[blockIdx.x] = lds[0];
}

__global__ __launch_bounds__(256) void scan_boffs(const int* __restrict__ bsum,
                                                  int* __restrict__ boffs) {
    __shared__ int lds[256];
    const int t = threadIdx.x;
    lds[t] = (t < SCAN_NB) ? bsum[t] : 0;
    __syncthreads();
    #pragma unroll
    for (int off = 1; off < 256; off <<= 1) {
        int add = (t >= off) ? lds[t - off] : 0;
        __syncthreads();
        lds[t] += add;
        __syncthreads();
    }
    boffs[t] = (t == 0) ? 0 : lds[t - 1];   // exclusive
}

__global__ __launch_bounds__(256) void scan_write(const int* __restrict__ deg,
                                                  const int* __restrict__ boffs,
                                                  int* __restrict__ rp) {
    __shared__ int lds[256];
    const int t = threadIdx.x;
    int i = blockIdx.x * 256 + t;
    int v = (i < N_NODES) ? deg[i] + 1 : 0;
    lds[t] = v;
    __syncthreads();
    #pragma unroll
    for (int off = 1; off < 256; off <<= 1) {
        int add = (t >= off) ? lds[t - off] : 0;
        __syncthreads();
        lds[t] += add;
        __syncthreads();
    }
    if (i < N_NODES) rp[i] = boffs[blockIdx.x] + lds[t] - v;
    if (i == N_NODES - 1) rp[N_NODES] = boffs[blockIdx.x] + lds[t];
}

// one 8B store per edge: (src, weight-bits); self-loop takes the reserved last slot
__global__ void scatter_kernel(const int* __restrict__ ei, const float* __restrict__ dinv,
                               const int* __restrict__ rp, int* __restrict__ cursor,
                               int2* __restrict__ csr) {
    int e = blockIdx.x * blockDim.x + threadIdx.x;
    if (e >= N_EDGES + N_NODES) return;
    int pos, src; float w;
    if (e < N_EDGES) {
        src = ei[e]; int dst = ei[N_EDGES + e];
        w = dinv[src] * dinv[dst];
        pos = rp[dst] + atomicAdd(&cursor[dst], 1);
    } else {
        src = e - N_EDGES;
        w = dinv[src] * dinv[src];
        pos = rp[src + 1] - 1;             // reserved slot, no atomic
    }
    csr[pos] = make_int2(src, __float_as_int(w));
}

// ---------------- SpMM: out[r] = sum_e w * h[src], bf16 gather, unroll-8 ----------------
// C8 = C/8 lanes per row; optional f32 output; optional fused BN-stats atomics
template<int C8, bool OUTF32, bool STATS>
__global__ __launch_bounds__(256) void spmm_b(const int* __restrict__ rp,
                                              const int2* __restrict__ csr,
                                              const __bf16* __restrict__ h,
                                              void* __restrict__ outp,
                                              float* __restrict__ stats) {
    constexpr int C = C8 * 8;
    constexpr int RPB = 256 / C8;
    const int r = blockIdx.x * RPB + threadIdx.x / C8;
    const int l = threadIdx.x % C8;
    const bool valid = r < N_NODES;
    float acc0[8] = {}, acc1[8] = {};
    if (valid) {
        const bf16x8* __restrict__ h8 = (const bf16x8*)h;
        const int e0 = rp[r], e1 = rp[r + 1];
        int e = e0;
        for (; e + 8 <= e1; e += 8) {
            int2 p[8];
            #pragma unroll
            for (int u = 0; u < 8; ++u) p[u] = csr[e + u];
            bf16x8 v[8];
            #pragma unroll
            for (int u = 0; u < 8; ++u) v[u] = h8[(long)p[u].x * C8 + l];
            #pragma unroll
            for (int u = 0; u < 8; ++u) {
                float w = __int_as_float(p[u].y);
                #pragma unroll
                for (int j = 0; j < 8; ++j) {
                    if (u & 1) acc1[j] = fmaf(w, (float)v[u][j], acc1[j]);
                    else       acc0[j] = fmaf(w, (float)v[u][j], acc0[j]);
                }
            }
        }
        for (; e + 2 <= e1; e += 2) {
            int2 p0 = csr[e], p1 = csr[e + 1];
            float w0 = __int_as_float(p0.y), w1 = __int_as_float(p1.y);
            bf16x8 v0 = h8[(long)p0.x * C8 + l];
            bf16x8 v1 = h8[(long)p1.x * C8 + l];
            #pragma unroll
            for (int j = 0; j < 8; ++j) {
                acc0[j] = fmaf(w0, (float)v0[j], acc0[j]);
                acc1[j] = fmaf(w1, (float)v1[j], acc1[j]);
            }
        }
        if (e < e1) {
            int2 p0 = csr[e];
            float w0 = __int_as_float(p0.y);
            bf16x8 v0 = h8[(long)p0.x * C8 + l];
            #pragma unroll
            for (int j = 0; j < 8; ++j) acc0[j] = fmaf(w0, (float)v0[j], acc0[j]);
        }
    }
    float res[8];
    #pragma unroll
    for (int j = 0; j < 8; ++j) res[j] = acc0[j] + acc1[j];
    if (valid) {
        if (OUTF32) {
            float* o = (float*)outp + (long)r * C + l * 8;
            ((float4*)o)[0] = make_float4(res[0], res[1], res[2], res[3]);
            ((float4*)o)[1] = make_float4(res[4], res[5], res[6], res[7]);
        } else {
            bf16x8 ob;
            #pragma unroll
            for (int j = 0; j < 8; ++j) ob[j] = (__bf16)res[j];
            ((bf16x8*)outp)[(long)r * C8 + l] = ob;
        }
    }
    if (STATS) {
        __shared__ float sred[256][8];
        __shared__ float qred[256][8];
        #pragma unroll
        for (int j = 0; j < 8; ++j) {
            float v = valid ? res[j] : 0.f;
            sred[threadIdx.x][j] = v;
            qred[threadIdx.x][j] = v * v;
        }
        __syncthreads();
        if (threadIdx.x < C8) {
            float s[8] = {}, q[8] = {};
            #pragma unroll
            for (int g = 0; g < RPB; ++g) {
                #pragma unroll
                for (int j = 0; j < 8; ++j) {
                    s[j] += sred[g * C8 + threadIdx.x][j];
                    q[j] += qred[g * C8 + threadIdx.x][j];
                }
            }
            #pragma unroll
            for (int j = 0; j < 8; ++j) {
                atomicAdd(&stats[threadIdx.x * 8 + j], s[j]);
                atomicAdd(&stats[C + threadIdx.x * 8 + j], q[j]);
            }
        }
    }
}

// ---------------- bf16 MFMA GEMM with LDS-staged A and optional fused BN+leaky on A ----
template<int K, int NC, bool FUSE_BN, bool RELU>
__global__ __launch_bounds__(256) void gemm_tile(const __bf16* __restrict__ A,
                                                 const __bf16* __restrict__ W,
                                                 const float* __restrict__ ss,
                                                 __bf16* __restrict__ C,
                                                 int M) {
    constexpr int NW = NC / 64;
    constexpr int MW = 4 / NW;
    constexpr int BM = MW * 64;
    constexpr int LSTR = 40;
    __shared__ __bf16 As[BM][LSTR];

    const int tid = threadIdx.x;
    const int wave = tid >> 6, lane = tid & 63;
    const int ln15 = lane & 15, kg = lane >> 4;
    const int wm = wave / NW, wn = wave % NW;
    const int m0 = blockIdx.x * BM;

    const int srow = tid >> 2;
    const int schunk = tid & 3;

    f32x4 acc[4][4];
    #pragma unroll
    for (int i = 0; i < 4; ++i)
        #pragma unroll
        for (int j = 0; j < 4; ++j) acc[i][j] = (f32x4){0.f, 0.f, 0.f, 0.f};

    for (int kt = 0; kt < K; kt += 32) {
        #pragma unroll
        for (int p = 0; p < MW; ++p) {
            int gr = m0 + p * 64 + srow;
            gr = gr < M ? gr : M - 1;
            bf16x8 v = *(const bf16x8*)(A + (long)gr * K + kt + schunk * 8);
            if (FUSE_BN) {
                const f32x4* ss4 = (const f32x4*)ss;
                int ci = (kt + schunk * 8) >> 2;
                f32x4 sc0 = ss4[ci],            sc1 = ss4[ci + 1];
                f32x4 sh0 = ss4[(K >> 2) + ci], sh1 = ss4[(K >> 2) + ci + 1];
                float f[8];
                #pragma unroll
                for (int j = 0; j < 4; ++j) {
                    f[j]     = fmaf((float)v[j],     sc0[j], sh0[j]);
                    f[j + 4] = fmaf((float)v[j + 4], sc1[j], sh1[j]);
                }
                if (RELU) {
                    #pragma unroll
                    for (int j = 0; j < 8; ++j) f[j] = f[j] > 0.f ? f[j] : SLOPE * f[j];
                }
                #pragma unroll
                for (int j = 0; j < 8; ++j) v[j] = (__bf16)f[j];
            }
            *(bf16x8*)(&As[p * 64 + srow][schunk * 8]) = v;
        }
        __syncthreads();
        bf16x8 b[4];
        #pragma unroll
        for (int j = 0; j < 4; ++j)
            b[j] = *(const bf16x8*)(W + (long)(wn * 64 + j * 16 + ln15) * K + kt + kg * 8);
        #pragma unroll
        for (int i = 0; i < 4; ++i) {
            bf16x8 a = *(const bf16x8*)(&As[wm * 64 + i * 16 + ln15][kg * 8]);
            #pragma unroll
            for (int j = 0; j < 4; ++j)
                acc[i][j] = __builtin_amdgcn_mfma_f32_16x16x32_bf16(a, b[j], acc[i][j], 0, 0, 0);
        }
        __syncthreads();
    }
    #pragma unroll
    for (int i = 0; i < 4; ++i) {
        #pragma unroll
        for (int j = 0; j < 4; ++j) {
            #pragma unroll
            for (int q = 0; q < 4; ++q) {
                int r = m0 + wm * 64 + i * 16 + kg * 4 + q;
                if (r < M) C[(long)r * NC + wn * 64 + j * 16 + ln15] = (__bf16)acc[i][j][q];
            }
        }
    }
}

// ---------------- BN stats (layer-0 only, reads gemm output) ----------------
#define NB_STATS 128
template<int C, bool BF16>
__global__ __launch_bounds__(256) void bn_stats(const void* __restrict__ hp,
                                                float* __restrict__ partial) {
    constexpr int LPR = C / 4;
    constexpr int RPI = 256 / LPR;
    const int chunk = threadIdx.x % LPR;
    const int rof   = threadIdx.x / LPR;
    float s[4] = {}, s2[4] = {};
    for (int r = blockIdx.x * RPI + rof; r < N_NODES; r += NB_STATS * RPI) {
        float v[4];
        if (BF16) {
            bf16x4 x = ((const bf16x4*)hp)[(long)r * LPR + chunk];
            #pragma unroll
            for (int j = 0; j < 4; ++j) v[j] = (float)x[j];
        } else {
            float4 x = ((const float4*)hp)[(long)r * LPR + chunk];
            v[0] = x.x; v[1] = x.y; v[2] = x.z; v[3] = x.w;
        }
        #pragma unroll
        for (int j = 0; j < 4; ++j) { s[j] += v[j]; s2[j] += v[j] * v[j]; }
    }
    __shared__ float red[256 * 8];
    #pragma unroll
    for (int j = 0; j < 4; ++j) { red[threadIdx.x * 8 + j] = s[j]; red[threadIdx.x * 8 + 4 + j] = s2[j]; }
    __syncthreads();
    if (rof == 0) {
        #pragma unroll
        for (int g = 1; g < RPI; ++g) {
            #pragma unroll
            for (int j = 0; j < 4; ++j) {
                s[j]  += red[(g * LPR + chunk) * 8 + j];
                s2[j] += red[(g * LPR + chunk) * 8 + 4 + j];
            }
        }
        #pragma unroll
        for (int j = 0; j < 4; ++j) {
            partial[blockIdx.x * 2 * C + chunk * 4 + j]     = s[j];
            partial[blockIdx.x * 2 * C + C + chunk * 4 + j] = s2[j];
        }
    }
}

template<int C>
__global__ void bn_reduce(const float* __restrict__ partial, const float* __restrict__ g,
                          const float* __restrict__ be, float* __restrict__ ss) {
    int c = threadIdx.x;
    float s_0 = 0.f, s_1 = 0.f, q_0 = 0.f, q_1 = 0.f;
    #pragma unroll 4
    for (int b = 0; b < NB_STATS; b += 2) {
        s_0 += partial[b * 2 * C + c];
        q_0 += partial[b * 2 * C + C + c];
        s_1 += partial[(b + 1) * 2 * C + c];
        q_1 += partial[(b + 1) * 2 * C + C + c];
    }
    float s = s_0 + s_1, s2 = q_0 + q_1;
    const float invn = 1.0f / (float)N_NODES;
    float mean = s * invn;
    float var  = s2 * invn - mean * mean;
    float rstd = rsqrtf(var + EPSV);
    float sc = g[c] * rstd;
    ss[c] = sc;
    ss[C + c] = be[c] - mean * sc;
}

// stats already fully summed by spmm epilogue atomics
template<int C>
__global__ void bn_reduce_direct(const float* __restrict__ stats, const float* __restrict__ g,
                                 const float* __restrict__ be, float* __restrict__ ss) {
    int c = threadIdx.x;
    const float invn = 1.0f / (float)N_NODES;
    float mean = stats[c] * invn;
    float var  = stats[C + c] * invn - mean * mean;
    float rstd = rsqrtf(var + EPSV);
    float sc = g[c] * rstd;
    ss[c] = sc;
    ss[C + c] = be[c] - mean * sc;
}

// ---------------- BN apply (final layer, f32 in-place) ----------------
template<int C>
__global__ __launch_bounds__(256) void bn_apply_f32(float* __restrict__ h,
                                                    const float* __restrict__ ss) {
    constexpr int LPR = C / 4;
    const long total = (long)N_NODES * LPR;
    const long stride = (long)gridDim.x * blockDim.x;
    for (long idx = (long)blockIdx.x * blockDim.x + threadIdx.x; idx < total; idx += stride) {
        int chunk = (int)(idx % LPR);
        float4 sc = ((const float4*)ss)[chunk];
        float4 sh = ((const float4*)(ss + C))[chunk];
        float4 x = ((float4*)h)[idx];
        x.x = fmaf(x.x, sc.x, sh.x); x.y = fmaf(x.y, sc.y, sh.y);
        x.z = fmaf(x.z, sc.z, sh.z); x.w = fmaf(x.w, sc.w, sh.w);
        ((float4*)h)[idx] = x;
    }
}

extern "C" void kernel_launch(void* const* d_in, const int* in_sizes, int n_in,
                              void* d_out, int out_size, void* d_ws, size_t ws_size,
                              hipStream_t stream) {
    const float* x   = (const float*)d_in[0];
    const int*   ei  = (const int*)  d_in[1];
    const float* W0  = (const float*)d_in[2];
    const float* g0  = (const float*)d_in[4];
    const float* be0 = (const float*)d_in[5];
    const float* W1  = (const float*)d_in[6];
    const float* g1  = (const float*)d_in[8];
    const float* be1 = (const float*)d_in[9];
    const float* W2  = (const float*)d_in[10];
    const float* g2  = (const float*)d_in[12];
    const float* be2 = (const float*)d_in[13];
    float* out = (float*)d_out;

    char* wsb = (char*)d_ws;
    auto alloc = [&](size_t bytes) { char* p = wsb; wsb += (bytes + 255) & ~255UL; return p; };
    int*    deg     = (int*)   alloc(N_NODES * 4);
    int*    rp      = (int*)   alloc((N_NODES + 4) * 4);
    int*    cursor  = (int*)   alloc(N_NODES * 4);
    float*  dinv    = (float*) alloc(N_NODES * 4);
    int*    bsum    = (int*)   alloc(256 * 4);
    int*    boffs   = (int*)   alloc(257 * 4);
    float*  partial = (float*) alloc(NB_STATS * 2 * DH * 4);
    float*  statsum = (float*) alloc(2 * DH * 4);
    float*  ss      = (float*) alloc(2 * DH * 4);
    int2*   csr     = (int2*)  alloc((size_t)(N_EDGES + N_NODES) * 8);
    __bf16* w0b     = (__bf16*)alloc(DH * DIN * 2);
    __bf16* w1b     = (__bf16*)alloc(DH * DH * 2);
    __bf16* w2b     = (__bf16*)alloc(DOUT * DH * 2);
    __bf16* xb      = (__bf16*)alloc((size_t)N_NODES * DIN * 2);
    __bf16* bf0     = (__bf16*)alloc((size_t)N_NODES * DH * 2);
    __bf16* bf1     = (__bf16*)alloc((size_t)N_NODES * DH * 2);

    // ---- casts ----
    cast_kernel<<<(DH * DIN / 4 + 255) / 256, 256, 0, stream>>>(W0, w0b, DH * DIN / 4);
    cast_kernel<<<(DH * DH  / 4 + 255) / 256, 256, 0, stream>>>(W1, w1b, DH * DH / 4);
    cast_kernel<<<(DOUT * DH / 4 + 255) / 256, 256, 0, stream>>>(W2, w2b, DOUT * DH / 4);
    cast_kernel<<<(N_NODES * DIN / 4 + 255) / 256, 256, 0, stream>>>(x, xb, N_NODES * DIN / 4);

    // ---- CSR build ----
    hipMemsetAsync(deg, 0, N_NODES * 4, stream);
    hipMemsetAsync(cursor, 0, N_NODES * 4, stream);
    deg_kernel<<<(N_EDGES + 255) / 256, 256, 0, stream>>>(ei + N_EDGES, deg);
    dinv_kernel<<<(N_NODES + 255) / 256, 256, 0, stream>>>(deg, dinv);
    scan_bsum<<<SCAN_NB, 256, 0, stream>>>(deg, bsum);
    scan_boffs<<<1, 256, 0, stream>>>(bsum, boffs);
    scan_write<<<SCAN_NB, 256, 0, stream>>>(deg, boffs, rp);
    scatter_kernel<<<(N_EDGES + N_NODES + 255) / 256, 256, 0, stream>>>(
        ei, dinv, rp, cursor, csr);

    // ---- layer 0: aggregate xb (C=128), gemm, stats ----
    spmm_b<DIN / 8, false, false><<<(N_NODES * (DIN / 8) + 255) / 256, 256, 0, stream>>>(
        rp, csr, xb, bf0, nullptr);
    gemm_tile<DIN, DH, false, false><<<(N_NODES + 63) / 64, 256, 0, stream>>>(
        bf0, w0b, nullptr, bf1, N_NODES);
    bn_stats<DH, true><<<NB_STATS, 256, 0, stream>>>(bf1, partial);
    bn_reduce<DH><<<1, DH, 0, stream>>>(partial, g0, be0, ss);

    // ---- layer 1: gemm (fused BN0+leaky) -> aggregate (fused stats) ----
    gemm_tile<DH, DH, true, true><<<(N_NODES + 63) / 64, 256, 0, stream>>>(
        bf1, w1b, ss, bf0, N_NODES);
    hipMemsetAsync(statsum, 0, 2 * DH * 4, stream);
    spmm_b<DH / 8, false, true><<<(N_NODES * (DH / 8) + 255) / 256, 256, 0, stream>>>(
        rp, csr, bf0, bf1, statsum);
    bn_reduce_direct<DH><<<1, DH, 0, stream>>>(statsum, g1, be1, ss);

    // ---- layer 2: gemm (fused BN1+leaky) -> aggregate f32 out (fused stats) -> BN ----
    gemm_tile<DH, DOUT, true, true><<<(N_NODES + 127) / 128, 256, 0, stream>>>(
        bf1, w2b, ss, bf0, N_NODES);
    hipMemsetAsync(statsum, 0, 2 * DOUT * 4, stream);
    spmm_b<DOUT / 8, true, true><<<(N_NODES * (DOUT / 8) + 255) / 256, 256, 0, stream>>>(
        rp, csr, bf0, out, statsum);
    bn_reduce_direct<DOUT><<<1, DOUT, 0, stream>>>(statsum, g2, be2, ss);
    bn_apply_f32<DOUT><<<2048, 256, 0, stream>>>(out, ss);
}

// Round 7
// 403.826 us; speedup vs baseline: 5.1737x; 5.1737x over previous
//
#include <hip/hip_runtime.h>
#include <hip/hip_bf16.h>

#define N_NODES 50000
#define N_EDGES 800000
#define DIN 128
#define DH   256
#define DOUT 128
#define EPSV 1e-5f
#define SLOPE 0.01f
#define SCAN_NB ((N_NODES + 255) / 256)   // 196

typedef __bf16 bf16x8 __attribute__((ext_vector_type(8)));
typedef __bf16 bf16x4 __attribute__((ext_vector_type(4)));
typedef float  f32x4  __attribute__((ext_vector_type(4)));

// ---------------- cast f32 -> bf16 (weights and x) ----------------
__global__ void cast_kernel(const float* __restrict__ src, __bf16* __restrict__ dst, int n4) {
    int i = blockIdx.x * blockDim.x + threadIdx.x;
    if (i < n4) {
        float4 v = ((const float4*)src)[i];
        bf16x4 o; o[0] = (__bf16)v.x; o[1] = (__bf16)v.y; o[2] = (__bf16)v.z; o[3] = (__bf16)v.w;
        ((bf16x4*)dst)[i] = o;
    }
}

// ---------------- CSR build ----------------
__global__ void deg_kernel(const int* __restrict__ dst, int* __restrict__ deg) {
    int i = blockIdx.x * blockDim.x + threadIdx.x;
    if (i < N_EDGES) atomicAdd(&deg[dst[i]], 1);
}

__global__ void dinv_kernel(const int* __restrict__ deg, float* __restrict__ dinv) {
    int i = blockIdx.x * blockDim.x + threadIdx.x;
    if (i < N_NODES) dinv[i] = rsqrtf((float)deg[i] + 1.0f);  // +1 self-loop
}

__global__ __launch_bounds__(256) void scan_bsum(const int* __restrict__ deg,
                                                 int* __restrict__ bsum) {
    __shared__ int lds[256];
    int i = blockIdx.x * 256 + threadIdx.x;
    lds[threadIdx.x] = (i < N_NODES) ? deg[i] + 1 : 0;
    __syncthreads();
    #pragma unroll
    for (int off = 128; off > 0; off >>= 1) {
        if (threadIdx.x < off) lds[threadIdx.x] += lds[threadIdx.x + off];
        __syncthreads();
    }
    if (threadIdx.x == 0) bsum[blockIdx.x] = lds[0];
}

__global__ __launch_bounds__(256) void scan_boffs(const int* __restrict__ bsum,
                                                  int* __restrict__ boffs) {
    __shared__ int lds[256];
    const int t = threadIdx.x;
    lds[t] = (t < SCAN_NB) ? bsum[t] : 0;
    __syncthreads();
    #pragma unroll
    for (int off = 1; off < 256; off <<= 1) {
        int add = (t >= off) ? lds[t - off] : 0;
        __syncthreads();
        lds[t] += add;
        __syncthreads();
    }
    boffs[t] = (t == 0) ? 0 : lds[t - 1];   // exclusive
}

__global__ __launch_bounds__(256) void scan_write(const int* __restrict__ deg,
                                                  const int* __restrict__ boffs,
                                                  int* __restrict__ rp) {
    __shared__ int lds[256];
    const int t = threadIdx.x;
    int i = blockIdx.x * 256 + t;
    int v = (i < N_NODES) ? deg[i] + 1 : 0;
    lds[t] = v;
    __syncthreads();
    #pragma unroll
    for (int off = 1; off < 256; off <<= 1) {
        int add = (t >= off) ? lds[t - off] : 0;
        __syncthreads();
        lds[t] += add;
        __syncthreads();
    }
    if (i < N_NODES) rp[i] = boffs[blockIdx.x] + lds[t] - v;
    if (i == N_NODES - 1) rp[N_NODES] = boffs[blockIdx.x] + lds[t];
}

// one 8B store per edge: (src, weight-bits); self-loop takes the reserved last slot
__global__ void scatter_kernel(const int* __restrict__ ei, const float* __restrict__ dinv,
                               const int* __restrict__ rp, int* __restrict__ cursor,
                               int2* __restrict__ csr) {
    int e = blockIdx.x * blockDim.x + threadIdx.x;
    if (e >= N_EDGES + N_NODES) return;
    int pos, src; float w;
    if (e < N_EDGES) {
        src = ei[e]; int dst = ei[N_EDGES + e];
        w = dinv[src] * dinv[dst];
        pos = rp[dst] + atomicAdd(&cursor[dst], 1);
    } else {
        src = e - N_EDGES;
        w = dinv[src] * dinv[src];
        pos = rp[src + 1] - 1;             // reserved slot, no atomic
    }
    csr[pos] = make_int2(src, __float_as_int(w));
}

// ---------------- SpMM: out[r] = sum_e w * h[src], bf16 gather, unroll-8 ----------------
template<int C8, bool OUTF32>
__global__ __launch_bounds__(256) void spmm_b(const int* __restrict__ rp,
                                              const int2* __restrict__ csr,
                                              const __bf16* __restrict__ h,
                                              void* __restrict__ outp) {
    constexpr int C = C8 * 8;
    constexpr int RPB = 256 / C8;
    const int r = blockIdx.x * RPB + threadIdx.x / C8;
    const int l = threadIdx.x % C8;
    if (r >= N_NODES) return;
    const bf16x8* __restrict__ h8 = (const bf16x8*)h;
    const int e0 = rp[r], e1 = rp[r + 1];
    float acc0[8] = {}, acc1[8] = {};
    int e = e0;
    for (; e + 8 <= e1; e += 8) {
        int2 p[8];
        #pragma unroll
        for (int u = 0; u < 8; ++u) p[u] = csr[e + u];
        bf16x8 v[8];
        #pragma unroll
        for (int u = 0; u < 8; ++u) v[u] = h8[(long)p[u].x * C8 + l];
        #pragma unroll
        for (int u = 0; u < 8; ++u) {
            float w = __int_as_float(p[u].y);
            #pragma unroll
            for (int j = 0; j < 8; ++j) {
                if (u & 1) acc1[j] = fmaf(w, (float)v[u][j], acc1[j]);
                else       acc0[j] = fmaf(w, (float)v[u][j], acc0[j]);
            }
        }
    }
    for (; e + 2 <= e1; e += 2) {
        int2 p0 = csr[e], p1 = csr[e + 1];
        float w0 = __int_as_float(p0.y), w1 = __int_as_float(p1.y);
        bf16x8 v0 = h8[(long)p0.x * C8 + l];
        bf16x8 v1 = h8[(long)p1.x * C8 + l];
        #pragma unroll
        for (int j = 0; j < 8; ++j) {
            acc0[j] = fmaf(w0, (float)v0[j], acc0[j]);
            acc1[j] = fmaf(w1, (float)v1[j], acc1[j]);
        }
    }
    if (e < e1) {
        int2 p0 = csr[e];
        float w0 = __int_as_float(p0.y);
        bf16x8 v0 = h8[(long)p0.x * C8 + l];
        #pragma unroll
        for (int j = 0; j < 8; ++j) acc0[j] = fmaf(w0, (float)v0[j], acc0[j]);
    }
    float res[8];
    #pragma unroll
    for (int j = 0; j < 8; ++j) res[j] = acc0[j] + acc1[j];
    if (OUTF32) {
        float* o = (float*)outp + (long)r * C + l * 8;
        ((float4*)o)[0] = make_float4(res[0], res[1], res[2], res[3]);
        ((float4*)o)[1] = make_float4(res[4], res[5], res[6], res[7]);
    } else {
        bf16x8 ob;
        #pragma unroll
        for (int j = 0; j < 8; ++j) ob[j] = (__bf16)res[j];
        ((bf16x8*)outp)[(long)r * C8 + l] = ob;
    }
}

// ---------------- bf16 MFMA GEMM with LDS-staged A and optional fused BN+leaky on A ----
template<int K, int NC, bool FUSE_BN, bool RELU>
__global__ __launch_bounds__(256) void gemm_tile(const __bf16* __restrict__ A,
                                                 const __bf16* __restrict__ W,
                                                 const float* __restrict__ ss,
                                                 __bf16* __restrict__ C,
                                                 int M) {
    constexpr int NW = NC / 64;
    constexpr int MW = 4 / NW;
    constexpr int BM = MW * 64;
    constexpr int LSTR = 40;
    __shared__ __bf16 As[BM][LSTR];

    const int tid = threadIdx.x;
    const int wave = tid >> 6, lane = tid & 63;
    const int ln15 = lane & 15, kg = lane >> 4;
    const int wm = wave / NW, wn = wave % NW;
    const int m0 = blockIdx.x * BM;

    const int srow = tid >> 2;
    const int schunk = tid & 3;

    f32x4 acc[4][4];
    #pragma unroll
    for (int i = 0; i < 4; ++i)
        #pragma unroll
        for (int j = 0; j < 4; ++j) acc[i][j] = (f32x4){0.f, 0.f, 0.f, 0.f};

    for (int kt = 0; kt < K; kt += 32) {
        #pragma unroll
        for (int p = 0; p < MW; ++p) {
            int gr = m0 + p * 64 + srow;
            gr = gr < M ? gr : M - 1;
            bf16x8 v = *(const bf16x8*)(A + (long)gr * K + kt + schunk * 8);
            if (FUSE_BN) {
                const f32x4* ss4 = (const f32x4*)ss;
                int ci = (kt + schunk * 8) >> 2;
                f32x4 sc0 = ss4[ci],            sc1 = ss4[ci + 1];
                f32x4 sh0 = ss4[(K >> 2) + ci], sh1 = ss4[(K >> 2) + ci + 1];
                float f[8];
                #pragma unroll
                for (int j = 0; j < 4; ++j) {
                    f[j]     = fmaf((float)v[j],     sc0[j], sh0[j]);
                    f[j + 4] = fmaf((float)v[j + 4], sc1[j], sh1[j]);
                }
                if (RELU) {
                    #pragma unroll
                    for (int j = 0; j < 8; ++j) f[j] = f[j] > 0.f ? f[j] : SLOPE * f[j];
                }
                #pragma unroll
                for (int j = 0; j < 8; ++j) v[j] = (__bf16)f[j];
            }
            *(bf16x8*)(&As[p * 64 + srow][schunk * 8]) = v;
        }
        __syncthreads();
        bf16x8 b[4];
        #pragma unroll
        for (int j = 0; j < 4; ++j)
            b[j] = *(const bf16x8*)(W + (long)(wn * 64 + j * 16 + ln15) * K + kt + kg * 8);
        #pragma unroll
        for (int i = 0; i < 4; ++i) {
            bf16x8 a = *(const bf16x8*)(&As[wm * 64 + i * 16 + ln15][kg * 8]);
            #pragma unroll
            for (int j = 0; j < 4; ++j)
                acc[i][j] = __builtin_amdgcn_mfma_f32_16x16x32_bf16(a, b[j], acc[i][j], 0, 0, 0);
        }
        __syncthreads();
    }
    #pragma unroll
    for (int i = 0; i < 4; ++i) {
        #pragma unroll
        for (int j = 0; j < 4; ++j) {
            #pragma unroll
            for (int q = 0; q < 4; ++q) {
                int r = m0 + wm * 64 + i * 16 + kg * 4 + q;
                if (r < M) C[(long)r * NC + wn * 64 + j * 16 + ln15] = (__bf16)acc[i][j][q];
            }
        }
    }
}

// ---------------- BN stats: per-block partial sums (atomic-free) ----------------
#define NB_STATS 128
template<int C, bool BF16>
__global__ __launch_bounds__(256) void bn_stats(const void* __restrict__ hp,
                                                float* __restrict__ partial) {
    constexpr int LPR = C / 4;
    constexpr int RPI = 256 / LPR;
    const int chunk = threadIdx.x % LPR;
    const int rof   = threadIdx.x / LPR;
    float s[4] = {}, s2[4] = {};
    for (int r = blockIdx.x * RPI + rof; r < N_NODES; r += NB_STATS * RPI) {
        float v[4];
        if (BF16) {
            bf16x4 x = ((const bf16x4*)hp)[(long)r * LPR + chunk];
            #pragma unroll
            for (int j = 0; j < 4; ++j) v[j] = (float)x[j];
        } else {
            float4 x = ((const float4*)hp)[(long)r * LPR + chunk];
            v[0] = x.x; v[1] = x.y; v[2] = x.z; v[3] = x.w;
        }
        #pragma unroll
        for (int j = 0; j < 4; ++j) { s[j] += v[j]; s2[j] += v[j] * v[j]; }
    }
    __shared__ float red[256 * 8];
    #pragma unroll
    for (int j = 0; j < 4; ++j) { red[threadIdx.x * 8 + j] = s[j]; red[threadIdx.x * 8 + 4 + j] = s2[j]; }
    __syncthreads();
    if (rof == 0) {
        #pragma unroll
        for (int g = 1; g < RPI; ++g) {
            #pragma unroll
            for (int j = 0; j < 4; ++j) {
                s[j]  += red[(g * LPR + chunk) * 8 + j];
                s2[j] += red[(g * LPR + chunk) * 8 + 4 + j];
            }
        }
        #pragma unroll
        for (int j = 0; j < 4; ++j) {
            partial[blockIdx.x * 2 * C + chunk * 4 + j]     = s[j];
            partial[blockIdx.x * 2 * C + C + chunk * 4 + j] = s2[j];
        }
    }
}

template<int C>
__global__ void bn_reduce(const float* __restrict__ partial, const float* __restrict__ g,
                          const float* __restrict__ be, float* __restrict__ ss) {
    int c = threadIdx.x;
    float s_0 = 0.f, s_1 = 0.f, q_0 = 0.f, q_1 = 0.f;
    #pragma unroll 4
    for (int b = 0; b < NB_STATS; b += 2) {
        s_0 += partial[b * 2 * C + c];
        q_0 += partial[b * 2 * C + C + c];
        s_1 += partial[(b + 1) * 2 * C + c];
        q_1 += partial[(b + 1) * 2 * C + C + c];
    }
    float s = s_0 + s_1, s2 = q_0 + q_1;
    const float invn = 1.0f / (float)N_NODES;
    float mean = s * invn;
    float var  = s2 * invn - mean * mean;
    float rstd = rsqrtf(var + EPSV);
    float sc = g[c] * rstd;
    ss[c] = sc;
    ss[C + c] = be[c] - mean * sc;
}

// ---------------- BN apply (final layer, f32 in-place) ----------------
template<int C>
__global__ __launch_bounds__(256) void bn_apply_f32(float* __restrict__ h,
                                                    const float* __restrict__ ss) {
    constexpr int LPR = C / 4;
    const long total = (long)N_NODES * LPR;
    const long stride = (long)gridDim.x * blockDim.x;
    for (long idx = (long)blockIdx.x * blockDim.x + threadIdx.x; idx < total; idx += stride) {
        int chunk = (int)(idx % LPR);
        float4 sc = ((const float4*)ss)[chunk];
        float4 sh = ((const float4*)(ss + C))[chunk];
        float4 x = ((float4*)h)[idx];
        x.x = fmaf(x.x, sc.x, sh.x); x.y = fmaf(x.y, sc.y, sh.y);
        x.z = fmaf(x.z, sc.z, sh.z); x.w = fmaf(x.w, sc.w, sh.w);
        ((float4*)h)[idx] = x;
    }
}

extern "C" void kernel_launch(void* const* d_in, const int* in_sizes, int n_in,
                              void* d_out, int out_size, void* d_ws, size_t ws_size,
                              hipStream_t stream) {
    const float* x   = (const float*)d_in[0];
    const int*   ei  = (const int*)  d_in[1];
    const float* W0  = (const float*)d_in[2];
    const float* g0  = (const float*)d_in[4];
    const float* be0 = (const float*)d_in[5];
    const float* W1  = (const float*)d_in[6];
    const float* g1  = (const float*)d_in[8];
    const float* be1 = (const float*)d_in[9];
    const float* W2  = (const float*)d_in[10];
    const float* g2  = (const float*)d_in[12];
    const float* be2 = (const float*)d_in[13];
    float* out = (float*)d_out;

    char* wsb = (char*)d_ws;
    auto alloc = [&](size_t bytes) { char* p = wsb; wsb += (bytes + 255) & ~255UL; return p; };
    int*    deg     = (int*)   alloc(N_NODES * 4);
    int*    rp      = (int*)   alloc((N_NODES + 4) * 4);
    int*    cursor  = (int*)   alloc(N_NODES * 4);
    float*  dinv    = (float*) alloc(N_NODES * 4);
    int*    bsum    = (int*)   alloc(256 * 4);
    int*    boffs   = (int*)   alloc(257 * 4);
    float*  partial = (float*) alloc(NB_STATS * 2 * DH * 4);
    float*  ss      = (float*) alloc(2 * DH * 4);
    int2*   csr     = (int2*)  alloc((size_t)(N_EDGES + N_NODES) * 8);
    __bf16* w0b     = (__bf16*)alloc(DH * DIN * 2);
    __bf16* w1b     = (__bf16*)alloc(DH * DH * 2);
    __bf16* w2b     = (__bf16*)alloc(DOUT * DH * 2);
    __bf16* xb      = (__bf16*)alloc((size_t)N_NODES * DIN * 2);
    __bf16* bf0     = (__bf16*)alloc((size_t)N_NODES * DH * 2);
    __bf16* bf1     = (__bf16*)alloc((size_t)N_NODES * DH * 2);

    // ---- casts ----
    cast_kernel<<<(DH * DIN / 4 + 255) / 256, 256, 0, stream>>>(W0, w0b, DH * DIN / 4);
    cast_kernel<<<(DH * DH  / 4 + 255) / 256, 256, 0, stream>>>(W1, w1b, DH * DH / 4);
    cast_kernel<<<(DOUT * DH / 4 + 255) / 256, 256, 0, stream>>>(W2, w2b, DOUT * DH / 4);
    cast_kernel<<<(N_NODES * DIN / 4 + 255) / 256, 256, 0, stream>>>(x, xb, N_NODES * DIN / 4);

    // ---- CSR build ----
    hipMemsetAsync(deg, 0, N_NODES * 4, stream);
    hipMemsetAsync(cursor, 0, N_NODES * 4, stream);
    deg_kernel<<<(N_EDGES + 255) / 256, 256, 0, stream>>>(ei + N_EDGES, deg);
    dinv_kernel<<<(N_NODES + 255) / 256, 256, 0, stream>>>(deg, dinv);
    scan_bsum<<<SCAN_NB, 256, 0, stream>>>(deg, bsum);
    scan_boffs<<<1, 256, 0, stream>>>(bsum, boffs);
    scan_write<<<SCAN_NB, 256, 0, stream>>>(deg, boffs, rp);
    scatter_kernel<<<(N_EDGES + N_NODES + 255) / 256, 256, 0, stream>>>(
        ei, dinv, rp, cursor, csr);

    // ---- layer 0: aggregate xb (C=128), gemm, stats ----
    spmm_b<DIN / 8, false><<<(N_NODES * (DIN / 8) + 255) / 256, 256, 0, stream>>>(
        rp, csr, xb, bf0);
    gemm_tile<DIN, DH, false, false><<<(N_NODES + 63) / 64, 256, 0, stream>>>(
        bf0, w0b, nullptr, bf1, N_NODES);
    bn_stats<DH, true><<<NB_STATS, 256, 0, stream>>>(bf1, partial);
    bn_reduce<DH><<<1, DH, 0, stream>>>(partial, g0, be0, ss);

    // ---- layer 1: gemm (fused BN0+leaky) -> aggregate -> stats ----
    gemm_tile<DH, DH, true, true><<<(N_NODES + 63) / 64, 256, 0, stream>>>(
        bf1, w1b, ss, bf0, N_NODES);
    spmm_b<DH / 8, false><<<(N_NODES * (DH / 8) + 255) / 256, 256, 0, stream>>>(
        rp, csr, bf0, bf1);
    bn_stats<DH, true><<<NB_STATS, 256, 0, stream>>>(bf1, partial);
    bn_reduce<DH><<<1, DH, 0, stream>>>(partial, g1, be1, ss);

    // ---- layer 2: gemm (fused BN1+leaky) -> aggregate f32 out -> stats -> BN ----
    gemm_tile<DH, DOUT, true, true><<<(N_NODES + 127) / 128, 256, 0, stream>>>(
        bf1, w2b, ss, bf0, N_NODES);
    spmm_b<DOUT / 8, true><<<(N_NODES * (DOUT / 8) + 255) / 256, 256, 0, stream>>>(
        rp, csr, bf0, out);
    bn_stats<DOUT, false><<<NB_STATS, 256, 0, stream>>>(out, partial);
    bn_reduce<DOUT><<<1, DOUT, 0, stream>>>(partial, g2, be2, ss);
    bn_apply_f32<DOUT><<<2048, 256, 0, stream>>>(out, ss);
}

// Round 8
// 400.028 us; speedup vs baseline: 5.2228x; 1.0095x over previous
//
#include <hip/hip_runtime.h>
#include <hip/hip_bf16.h>

#define N_NODES 50000
#define N_EDGES 800000
#define DIN 128
#define DH   256
#define DOUT 128
#define EPSV 1e-5f
#define SLOPE 0.01f
#define SCAN_NB ((N_NODES + 255) / 256)   // 196

typedef __bf16 bf16x8 __attribute__((ext_vector_type(8)));
typedef __bf16 bf16x4 __attribute__((ext_vector_type(4)));
typedef float  f32x4  __attribute__((ext_vector_type(4)));

// ---------------- cast f32 -> bf16 (weights) ----------------
__global__ void cast_kernel(const float* __restrict__ src, __bf16* __restrict__ dst, int n4) {
    int i = blockIdx.x * blockDim.x + threadIdx.x;
    if (i < n4) {
        float4 v = ((const float4*)src)[i];
        bf16x4 o; o[0] = (__bf16)v.x; o[1] = (__bf16)v.y; o[2] = (__bf16)v.z; o[3] = (__bf16)v.w;
        ((bf16x4*)dst)[i] = o;
    }
}

// ---------------- cast + row-scale by dinv: xb[r] = dinv[r] * x[r] ----------------
__global__ void cast_scale_kernel(const float* __restrict__ src, const float* __restrict__ dinv,
                                  __bf16* __restrict__ dst) {
    int i = blockIdx.x * blockDim.x + threadIdx.x;   // one bf16x8 unit
    if (i < N_NODES * DIN / 8) {
        int row = i / (DIN / 8);
        float d = dinv[row];
        float4 a = ((const float4*)src)[i * 2];
        float4 b = ((const float4*)src)[i * 2 + 1];
        bf16x8 o;
        o[0] = (__bf16)(a.x * d); o[1] = (__bf16)(a.y * d);
        o[2] = (__bf16)(a.z * d); o[3] = (__bf16)(a.w * d);
        o[4] = (__bf16)(b.x * d); o[5] = (__bf16)(b.y * d);
        o[6] = (__bf16)(b.z * d); o[7] = (__bf16)(b.w * d);
        ((bf16x8*)dst)[i] = o;
    }
}

// ---------------- CSR build ----------------
__global__ void deg_kernel(const int* __restrict__ dst, int* __restrict__ deg) {
    int i = blockIdx.x * blockDim.x + threadIdx.x;
    if (i < N_EDGES) atomicAdd(&deg[dst[i]], 1);
}

__global__ void dinv_kernel(const int* __restrict__ deg, float* __restrict__ dinv) {
    int i = blockIdx.x * blockDim.x + threadIdx.x;
    if (i < N_NODES) dinv[i] = rsqrtf((float)deg[i] + 1.0f);  // +1 self-loop
}

__global__ __launch_bounds__(256) void scan_bsum(const int* __restrict__ deg,
                                                 int* __restrict__ bsum) {
    __shared__ int lds[256];
    int i = blockIdx.x * 256 + threadIdx.x;
    lds[threadIdx.x] = (i < N_NODES) ? deg[i] + 1 : 0;
    __syncthreads();
    #pragma unroll
    for (int off = 128; off > 0; off >>= 1) {
        if (threadIdx.x < off) lds[threadIdx.x] += lds[threadIdx.x + off];
        __syncthreads();
    }
    if (threadIdx.x == 0) bsum[blockIdx.x] = lds[0];
}

__global__ __launch_bounds__(256) void scan_boffs(const int* __restrict__ bsum,
                                                  int* __restrict__ boffs) {
    __shared__ int lds[256];
    const int t = threadIdx.x;
    lds[t] = (t < SCAN_NB) ? bsum[t] : 0;
    __syncthreads();
    #pragma unroll
    for (int off = 1; off < 256; off <<= 1) {
        int add = (t >= off) ? lds[t - off] : 0;
        __syncthreads();
        lds[t] += add;
        __syncthreads();
    }
    boffs[t] = (t == 0) ? 0 : lds[t - 1];   // exclusive
}

__global__ __launch_bounds__(256) void scan_write(const int* __restrict__ deg,
                                                  const int* __restrict__ boffs,
                                                  int* __restrict__ rp) {
    __shared__ int lds[256];
    const int t = threadIdx.x;
    int i = blockIdx.x * 256 + t;
    int v = (i < N_NODES) ? deg[i] + 1 : 0;
    lds[t] = v;
    __syncthreads();
    #pragma unroll
    for (int off = 1; off < 256; off <<= 1) {
        int add = (t >= off) ? lds[t - off] : 0;
        __syncthreads();
        lds[t] += add;
        __syncthreads();
    }
    if (i < N_NODES) rp[i] = boffs[blockIdx.x] + lds[t] - v;
    if (i == N_NODES - 1) rp[N_NODES] = boffs[blockIdx.x] + lds[t];
}

// weightless CSR: one 4B store per edge; self-loop takes the reserved last slot
__global__ void scatter_kernel(const int* __restrict__ ei,
                               const int* __restrict__ rp, int* __restrict__ cursor,
                               int* __restrict__ csr) {
    int e = blockIdx.x * blockDim.x + threadIdx.x;
    if (e >= N_EDGES + N_NODES) return;
    int pos, src;
    if (e < N_EDGES) {
        src = ei[e]; int dst = ei[N_EDGES + e];
        pos = rp[dst] + atomicAdd(&cursor[dst], 1);
    } else {
        src = e - N_EDGES;
        pos = rp[src + 1] - 1;             // reserved slot, no atomic
    }
    csr[pos] = src;
}

// ---------------- SpMM: out[r] = dinv[r] * sum_e h[src[e]]  (h pre-scaled by dinv) ----
template<int C8, bool OUTF32>
__global__ __launch_bounds__(256) void spmm_b(const int* __restrict__ rp,
                                              const int* __restrict__ csr,
                                              const float* __restrict__ dinv,
                                              const __bf16* __restrict__ h,
                                              void* __restrict__ outp) {
    constexpr int C = C8 * 8;
    constexpr int RPB = 256 / C8;
    const int r = blockIdx.x * RPB + threadIdx.x / C8;
    const int l = threadIdx.x % C8;
    if (r >= N_NODES) return;
    const bf16x8* __restrict__ h8 = (const bf16x8*)h;
    const int e0 = rp[r], e1 = rp[r + 1];
    float acc0[8] = {}, acc1[8] = {};
    int e = e0;
    for (; e + 8 <= e1; e += 8) {
        int p[8];
        #pragma unroll
        for (int u = 0; u < 8; ++u) p[u] = csr[e + u];
        bf16x8 v[8];
        #pragma unroll
        for (int u = 0; u < 8; ++u) v[u] = h8[(long)p[u] * C8 + l];
        #pragma unroll
        for (int u = 0; u < 8; ++u) {
            #pragma unroll
            for (int j = 0; j < 8; ++j) {
                if (u & 1) acc1[j] += (float)v[u][j];
                else       acc0[j] += (float)v[u][j];
            }
        }
    }
    for (; e + 2 <= e1; e += 2) {
        int p0 = csr[e], p1 = csr[e + 1];
        bf16x8 v0 = h8[(long)p0 * C8 + l];
        bf16x8 v1 = h8[(long)p1 * C8 + l];
        #pragma unroll
        for (int j = 0; j < 8; ++j) {
            acc0[j] += (float)v0[j];
            acc1[j] += (float)v1[j];
        }
    }
    if (e < e1) {
        int p0 = csr[e];
        bf16x8 v0 = h8[(long)p0 * C8 + l];
        #pragma unroll
        for (int j = 0; j < 8; ++j) acc0[j] += (float)v0[j];
    }
    const float d = dinv[r];
    float res[8];
    #pragma unroll
    for (int j = 0; j < 8; ++j) res[j] = (acc0[j] + acc1[j]) * d;
    if (OUTF32) {
        float* o = (float*)outp + (long)r * C + l * 8;
        ((float4*)o)[0] = make_float4(res[0], res[1], res[2], res[3]);
        ((float4*)o)[1] = make_float4(res[4], res[5], res[6], res[7]);
    } else {
        bf16x8 ob;
        #pragma unroll
        for (int j = 0; j < 8; ++j) ob[j] = (__bf16)res[j];
        ((bf16x8*)outp)[(long)r * C8 + l] = ob;
    }
}

// ---------------- bf16 MFMA GEMM, double-buffered LDS, 1 barrier / K-step ----------------
// C[M x NC] = act(BN(A))[M x K] @ W[NC x K]^T ; optional output row-scale by dinv
template<int K, int NC, bool FUSE_BN, bool RELU, bool SCALE>
__global__ __launch_bounds__(256) void gemm_tile(const __bf16* __restrict__ A,
                                                 const __bf16* __restrict__ W,
                                                 const float* __restrict__ ss,
                                                 const float* __restrict__ dinv,
                                                 __bf16* __restrict__ C,
                                                 int M) {
    constexpr int NW = NC / 64;           // waves along N
    constexpr int MW = 4 / NW;            // waves along M
    constexpr int BM = MW * 64;           // block rows
    constexpr int NSTEP = K / 32;
    __shared__ __bf16 As[2][BM][40];      // padded stride

    const int tid = threadIdx.x;
    const int wave = tid >> 6, lane = tid & 63;
    const int ln15 = lane & 15, kg = lane >> 4;
    const int wm = wave / NW, wn = wave % NW;
    const int m0 = blockIdx.x * BM;
    const int srow = tid >> 2, schunk = tid & 3;

    int grow[MW];
    #pragma unroll
    for (int p = 0; p < MW; ++p) {
        int gr = m0 + p * 64 + srow;
        grow[p] = gr < M ? gr : M - 1;
    }

    f32x4 acc[4][4];
    #pragma unroll
    for (int i = 0; i < 4; ++i)
        #pragma unroll
        for (int j = 0; j < 4; ++j) acc[i][j] = (f32x4){0.f, 0.f, 0.f, 0.f};

#define LOAD_A(vv, kt_)                                                         \
    _Pragma("unroll")                                                           \
    for (int p = 0; p < MW; ++p)                                                \
        vv[p] = *(const bf16x8*)(A + (long)grow[p] * K + (kt_) + schunk * 8);

#define XFORM_A(vv, kt_)                                                        \
    if (FUSE_BN) {                                                              \
        const f32x4* ss4 = (const f32x4*)ss;                                    \
        int ci = ((kt_) + schunk * 8) >> 2;                                     \
        f32x4 sc0 = ss4[ci],            sc1 = ss4[ci + 1];                      \
        f32x4 sh0 = ss4[(K >> 2) + ci], sh1 = ss4[(K >> 2) + ci + 1];           \
        _Pragma("unroll")                                                       \
        for (int p = 0; p < MW; ++p) {                                          \
            float f[8];                                                         \
            _Pragma("unroll")                                                   \
            for (int j = 0; j < 4; ++j) {                                       \
                f[j]     = fmaf((float)vv[p][j],     sc0[j], sh0[j]);           \
                f[j + 4] = fmaf((float)vv[p][j + 4], sc1[j], sh1[j]);           \
            }                                                                   \
            if (RELU) {                                                         \
                _Pragma("unroll")                                               \
                for (int j = 0; j < 8; ++j) f[j] = f[j] > 0.f ? f[j] : SLOPE * f[j]; \
            }                                                                   \
            _Pragma("unroll")                                                   \
            for (int j = 0; j < 8; ++j) vv[p][j] = (__bf16)f[j];                \
        }                                                                       \
    }

#define WRITE_A(buf, vv)                                                        \
    _Pragma("unroll")                                                           \
    for (int p = 0; p < MW; ++p)                                                \
        *(bf16x8*)(&As[buf][p * 64 + srow][schunk * 8]) = vv[p];

    // prologue: tile0 -> LDS buf0; tile1 -> regs
    bf16x8 v0[MW], v[MW];
    LOAD_A(v0, 0)
    XFORM_A(v0, 0)
    WRITE_A(0, v0)
    if (NSTEP > 1) {
        LOAD_A(v, 32)
        XFORM_A(v, 32)
    }
    __syncthreads();

    int cur = 0;
    #pragma unroll
    for (int step = 0; step < NSTEP; ++step) {
        const int kt = step * 32;
        // write next tile (loaded last iteration) into the other buffer
        if (step + 1 < NSTEP) {
            WRITE_A(cur ^ 1, v)
        }
        // issue global loads for tile step+2 (latency hidden under MFMAs)
        bf16x8 vn[MW];
        if (step + 2 < NSTEP) {
            LOAD_A(vn, kt + 64)
        }
        // B fragments (L2-resident)
        bf16x8 b[4];
        #pragma unroll
        for (int j = 0; j < 4; ++j)
            b[j] = *(const bf16x8*)(W + (long)(wn * 64 + j * 16 + ln15) * K + kt + kg * 8);
        // compute tile step
        #pragma unroll
        for (int i = 0; i < 4; ++i) {
            bf16x8 a = *(const bf16x8*)(&As[cur][wm * 64 + i * 16 + ln15][kg * 8]);
            #pragma unroll
            for (int j = 0; j < 4; ++j)
                acc[i][j] = __builtin_amdgcn_mfma_f32_16x16x32_bf16(a, b[j], acc[i][j], 0, 0, 0);
        }
        if (step + 2 < NSTEP) {
            XFORM_A(vn, kt + 64)
            #pragma unroll
            for (int p = 0; p < MW; ++p) v[p] = vn[p];
        }
        __syncthreads();
        cur ^= 1;
    }
#undef LOAD_A
#undef XFORM_A
#undef WRITE_A

    // epilogue: optional row-scale by dinv, store bf16
    #pragma unroll
    for (int i = 0; i < 4; ++i) {
        #pragma unroll
        for (int q = 0; q < 4; ++q) {
            int r = m0 + wm * 64 + i * 16 + kg * 4 + q;
            if (r < M) {
                float d = SCALE ? dinv[r] : 1.0f;
                #pragma unroll
                for (int j = 0; j < 4; ++j)
                    C[(long)r * NC + wn * 64 + j * 16 + ln15] = (__bf16)(acc[i][j][q] * d);
            }
        }
    }
}

// ---------------- BN stats: per-block partial sums (atomic-free) ----------------
#define NB_STATS 128
template<int C, bool BF16>
__global__ __launch_bounds__(256) void bn_stats(const void* __restrict__ hp,
                                                float* __restrict__ partial) {
    constexpr int LPR = C / 4;
    constexpr int RPI = 256 / LPR;
    const int chunk = threadIdx.x % LPR;
    const int rof   = threadIdx.x / LPR;
    float s[4] = {}, s2[4] = {};
    for (int r = blockIdx.x * RPI + rof; r < N_NODES; r += NB_STATS * RPI) {
        float v[4];
        if (BF16) {
            bf16x4 x = ((const bf16x4*)hp)[(long)r * LPR + chunk];
            #pragma unroll
            for (int j = 0; j < 4; ++j) v[j] = (float)x[j];
        } else {
            float4 x = ((const float4*)hp)[(long)r * LPR + chunk];
            v[0] = x.x; v[1] = x.y; v[2] = x.z; v[3] = x.w;
        }
        #pragma unroll
        for (int j = 0; j < 4; ++j) { s[j] += v[j]; s2[j] += v[j] * v[j]; }
    }
    __shared__ float red[256 * 8];
    #pragma unroll
    for (int j = 0; j < 4; ++j) { red[threadIdx.x * 8 + j] = s[j]; red[threadIdx.x * 8 + 4 + j] = s2[j]; }
    __syncthreads();
    if (rof == 0) {
        #pragma unroll
        for (int g = 1; g < RPI; ++g) {
            #pragma unroll
            for (int j = 0; j < 4; ++j) {
                s[j]  += red[(g * LPR + chunk) * 8 + j];
                s2[j] += red[(g * LPR + chunk) * 8 + 4 + j];
            }
        }
        #pragma unroll
        for (int j = 0; j < 4; ++j) {
            partial[blockIdx.x * 2 * C + chunk * 4 + j]     = s[j];
            partial[blockIdx.x * 2 * C + C + chunk * 4 + j] = s2[j];
        }
    }
}

template<int C>
__global__ void bn_reduce(const float* __restrict__ partial, const float* __restrict__ g,
                          const float* __restrict__ be, float* __restrict__ ss) {
    int c = threadIdx.x;
    float s_0 = 0.f, s_1 = 0.f, q_0 = 0.f, q_1 = 0.f;
    #pragma unroll 4
    for (int b = 0; b < NB_STATS; b += 2) {
        s_0 += partial[b * 2 * C + c];
        q_0 += partial[b * 2 * C + C + c];
        s_1 += partial[(b + 1) * 2 * C + c];
        q_1 += partial[(b + 1) * 2 * C + C + c];
    }
    float s = s_0 + s_1, s2 = q_0 + q_1;
    const float invn = 1.0f / (float)N_NODES;
    float mean = s * invn;
    float var  = s2 * invn - mean * mean;
    float rstd = rsqrtf(var + EPSV);
    float sc = g[c] * rstd;
    ss[c] = sc;
    ss[C + c] = be[c] - mean * sc;
}

// ---------------- BN apply (final layer, f32 in-place) ----------------
template<int C>
__global__ __launch_bounds__(256) void bn_apply_f32(float* __restrict__ h,
                                                    const float* __restrict__ ss) {
    constexpr int LPR = C / 4;
    const long total = (long)N_NODES * LPR;
    const long stride = (long)gridDim.x * blockDim.x;
    for (long idx = (long)blockIdx.x * blockDim.x + threadIdx.x; idx < total; idx += stride) {
        int chunk = (int)(idx % LPR);
        float4 sc = ((const float4*)ss)[chunk];
        float4 sh = ((const float4*)(ss + C))[chunk];
        float4 x = ((float4*)h)[idx];
        x.x = fmaf(x.x, sc.x, sh.x); x.y = fmaf(x.y, sc.y, sh.y);
        x.z = fmaf(x.z, sc.z, sh.z); x.w = fmaf(x.w, sc.w, sh.w);
        ((float4*)h)[idx] = x;
    }
}

extern "C" void kernel_launch(void* const* d_in, const int* in_sizes, int n_in,
                              void* d_out, int out_size, void* d_ws, size_t ws_size,
                              hipStream_t stream) {
    const float* x   = (const float*)d_in[0];
    const int*   ei  = (const int*)  d_in[1];
    const float* W0  = (const float*)d_in[2];
    const float* g0  = (const float*)d_in[4];
    const float* be0 = (const float*)d_in[5];
    const float* W1  = (const float*)d_in[6];
    const float* g1  = (const float*)d_in[8];
    const float* be1 = (const float*)d_in[9];
    const float* W2  = (const float*)d_in[10];
    const float* g2  = (const float*)d_in[12];
    const float* be2 = (const float*)d_in[13];
    float* out = (float*)d_out;

    char* wsb = (char*)d_ws;
    auto alloc = [&](size_t bytes) { char* p = wsb; wsb += (bytes + 255) & ~255UL; return p; };
    int*    deg     = (int*)   alloc(N_NODES * 4);
    int*    rp      = (int*)   alloc((N_NODES + 4) * 4);
    int*    cursor  = (int*)   alloc(N_NODES * 4);
    float*  dinv    = (float*) alloc(N_NODES * 4);
    int*    bsum    = (int*)   alloc(256 * 4);
    int*    boffs   = (int*)   alloc(257 * 4);
    float*  partial = (float*) alloc(NB_STATS * 2 * DH * 4);
    float*  ss      = (float*) alloc(2 * DH * 4);
    int*    csr     = (int*)   alloc((size_t)(N_EDGES + N_NODES) * 4);
    __bf16* w0b     = (__bf16*)alloc(DH * DIN * 2);
    __bf16* w1b     = (__bf16*)alloc(DH * DH * 2);
    __bf16* w2b     = (__bf16*)alloc(DOUT * DH * 2);
    __bf16* xb      = (__bf16*)alloc((size_t)N_NODES * DIN * 2);
    __bf16* bf0     = (__bf16*)alloc((size_t)N_NODES * DH * 2);
    __bf16* bf1     = (__bf16*)alloc((size_t)N_NODES * DH * 2);

    // ---- weight casts ----
    cast_kernel<<<(DH * DIN / 4 + 255) / 256, 256, 0, stream>>>(W0, w0b, DH * DIN / 4);
    cast_kernel<<<(DH * DH  / 4 + 255) / 256, 256, 0, stream>>>(W1, w1b, DH * DH / 4);
    cast_kernel<<<(DOUT * DH / 4 + 255) / 256, 256, 0, stream>>>(W2, w2b, DOUT * DH / 4);

    // ---- CSR build ----
    hipMemsetAsync(deg, 0, N_NODES * 4, stream);
    hipMemsetAsync(cursor, 0, N_NODES * 4, stream);
    deg_kernel<<<(N_EDGES + 255) / 256, 256, 0, stream>>>(ei + N_EDGES, deg);
    dinv_kernel<<<(N_NODES + 255) / 256, 256, 0, stream>>>(deg, dinv);
    scan_bsum<<<SCAN_NB, 256, 0, stream>>>(deg, bsum);
    scan_boffs<<<1, 256, 0, stream>>>(bsum, boffs);
    scan_write<<<SCAN_NB, 256, 0, stream>>>(deg, boffs, rp);
    scatter_kernel<<<(N_EDGES + N_NODES + 255) / 256, 256, 0, stream>>>(ei, rp, cursor, csr);

    // ---- x -> bf16 pre-scaled by dinv (needs dinv) ----
    cast_scale_kernel<<<(N_NODES * (DIN / 8) + 255) / 256, 256, 0, stream>>>(x, dinv, xb);

    // ---- layer 0: aggregate xb (C=128) -> gemm0 -> stats ----
    spmm_b<DIN / 8, false><<<(N_NODES * (DIN / 8) + 255) / 256, 256, 0, stream>>>(
        rp, csr, dinv, xb, bf0);
    gemm_tile<DIN, DH, false, false, false><<<(N_NODES + 63) / 64, 256, 0, stream>>>(
        bf0, w0b, nullptr, nullptr, bf1, N_NODES);
    bn_stats<DH, true><<<NB_STATS, 256, 0, stream>>>(bf1, partial);
    bn_reduce<DH><<<1, DH, 0, stream>>>(partial, g0, be0, ss);

    // ---- layer 1: gemm (fused BN0+leaky, out scaled by dinv) -> aggregate -> stats ----
    gemm_tile<DH, DH, true, true, true><<<(N_NODES + 63) / 64, 256, 0, stream>>>(
        bf1, w1b, ss, dinv, bf0, N_NODES);
    spmm_b<DH / 8, false><<<(N_NODES * (DH / 8) + 255) / 256, 256, 0, stream>>>(
        rp, csr, dinv, bf0, bf1);
    bn_stats<DH, true><<<NB_STATS, 256, 0, stream>>>(bf1, partial);
    bn_reduce<DH><<<1, DH, 0, stream>>>(partial, g1, be1, ss);

    // ---- layer 2: gemm (fused BN1+leaky, out scaled) -> aggregate f32 -> stats -> BN ----
    gemm_tile<DH, DOUT, true, true, true><<<(N_NODES + 127) / 128, 256, 0, stream>>>(
        bf1, w2b, ss, dinv, bf0, N_NODES);
    spmm_b<DOUT / 8, true><<<(N_NODES * (DOUT / 8) + 255) / 256, 256, 0, stream>>>(
        rp, csr, dinv, bf0, out);
    bn_stats<DOUT, false><<<NB_STATS, 256, 0, stream>>>(out, partial);
    bn_reduce<DOUT><<<1, DOUT, 0, stream>>>(partial, g2, be2, ss);
    bn_apply_f32<DOUT><<<2048, 256, 0, stream>>>(out, ss);
}